// Round 4
// baseline (444.270 us; speedup 1.0000x reference)
//
#include <hip/hip_runtime.h>

typedef __attribute__((ext_vector_type(4))) float f32x4;
typedef __attribute__((ext_vector_type(8))) short s16x8;

#define MFMA16(a, b, c) __builtin_amdgcn_mfma_f32_16x16x32_bf16((a), (b), (c), 0, 0, 0)

// round-to-nearest-even fp32 -> bf16 bits
__device__ __forceinline__ unsigned short f2bf_bits(float f) {
  unsigned int u = __float_as_uint(f);
  unsigned int r = (u + 0x7fffu + ((u >> 16) & 1u)) >> 16;
  return (unsigned short)r;
}

__device__ __forceinline__ void gl_lds16(const void* g, void* l) {
  __builtin_amdgcn_global_load_lds((const __attribute__((address_space(1))) void*)g,
                                   (__attribute__((address_space(3))) void*)l, 16, 0, 0);
}

// fp32 -> bf16 bulk convert, 4 elems/thread
__global__ __launch_bounds__(256) void f2bf_kernel(const float* __restrict__ in,
                                                   unsigned short* __restrict__ out, int n4) {
  int idx = blockIdx.x * 256 + threadIdx.x;
  int stride = gridDim.x * 256;
  for (int i = idx; i < n4; i += stride) {
    float4 v = ((const float4*)in)[i];
    ushort4 o;
    o.x = f2bf_bits(v.x); o.y = f2bf_bits(v.y);
    o.z = f2bf_bits(v.z); o.w = f2bf_bits(v.w);
    ((ushort4*)out)[i] = o;
  }
}

// convert the 4 [1024,1024] weights in one launch
__global__ __launch_bounds__(256) void f2bf_w4(const float* __restrict__ w0,
                                               const float* __restrict__ w1,
                                               const float* __restrict__ w2,
                                               const float* __restrict__ w3,
                                               unsigned short* __restrict__ o0,
                                               unsigned short* __restrict__ o1,
                                               unsigned short* __restrict__ o2,
                                               unsigned short* __restrict__ o3) {
  const int s = blockIdx.y;
  const float* in = (s == 0) ? w0 : (s == 1) ? w1 : (s == 2) ? w2 : w3;
  unsigned short* out = (s == 0) ? o0 : (s == 1) ? o1 : (s == 2) ? o2 : o3;
  int i = blockIdx.x * 256 + threadIdx.x;
  float4 v = ((const float4*)in)[i];
  ushort4 o;
  o.x = f2bf_bits(v.x); o.y = f2bf_bits(v.y);
  o.z = f2bf_bits(v.z); o.w = f2bf_bits(v.w);
  ((ushort4*)out)[i] = o;
}

// ---------------- GEMM core: 128x64 block tile, BK=64, XOR-swizzled LDS ----------------
// Wave tile 64x32 (acc 4x2 = 32 regs) -> low register pressure -> 5-6 blocks/CU.
// LDS slot (row, lc) holds source chunk lc^(row&7); frag read back with same XOR.
#define GEMM_CORE_128x64(A_, B_, K_)                                                  \
  f32x4 acc[4][2];                                                                    \
  _Pragma("unroll") for (int i = 0; i < 4; ++i)                                       \
      _Pragma("unroll") for (int j = 0; j < 2; ++j)                                   \
          acc[i][j] = (f32x4){0.f, 0.f, 0.f, 0.f};                                    \
  {                                                                                   \
    const int rb = tid >> 3;                                                          \
    const int cb = ((tid & 7) ^ (rb & 7)) * 8;                                        \
    _Pragma("unroll 1") for (int k0 = 0; k0 < (K_); k0 += 64) {                       \
      _Pragma("unroll") for (int i = 0; i < 4; ++i)                                   \
          gl_lds16((A_) + (size_t)(rb + 32 * i) * (K_) + k0 + cb,                     \
                   &Al[(tid + 256 * i) * 8]);                                         \
      _Pragma("unroll") for (int i = 0; i < 2; ++i)                                   \
          gl_lds16((B_) + (size_t)(rb + 32 * i) * (K_) + k0 + cb,                     \
                   &Bl[(tid + 256 * i) * 8]);                                         \
      __syncthreads();                                                                \
      _Pragma("unroll") for (int ks = 0; ks < 2; ++ks) {                              \
        s16x8 af[4], bfr[2];                                                          \
        const int pch = ((ks * 4 + quad) ^ (l15 & 7)) * 8;                            \
        _Pragma("unroll") for (int i = 0; i < 4; ++i)                                 \
            af[i] = *(const s16x8*)&Al[(wm + i * 16 + l15) * 64 + pch];               \
        _Pragma("unroll") for (int j = 0; j < 2; ++j)                                 \
            bfr[j] = *(const s16x8*)&Bl[(wn + j * 16 + l15) * 64 + pch];              \
        _Pragma("unroll") for (int i = 0; i < 4; ++i)                                 \
            _Pragma("unroll") for (int j = 0; j < 2; ++j)                             \
                acc[i][j] = MFMA16(af[i], bfr[j], acc[i][j]);                         \
      }                                                                               \
      __syncthreads();                                                                \
    }                                                                                 \
  }

// Fused QKV: blockIdx.y in [0,48): sel = y>>4, by = y&15. Q pre-scaled by 1/8.
__global__ __launch_bounds__(256, 5) void gemm_qkv(const unsigned short* __restrict__ A,
                                                   const unsigned short* __restrict__ Wq,
                                                   const unsigned short* __restrict__ Wk,
                                                   const unsigned short* __restrict__ Wv,
                                                   const float* __restrict__ bq,
                                                   const float* __restrict__ bk,
                                                   const float* __restrict__ bv,
                                                   unsigned short* __restrict__ Qo,
                                                   unsigned short* __restrict__ Ko,
                                                   unsigned short* __restrict__ Vt) {
  __shared__ unsigned short Al[128 * 64];
  __shared__ unsigned short Bl[64 * 64];
  const int tid = threadIdx.x;
  const int lane = tid & 63, wave = tid >> 6;
  const int l15 = lane & 15, quad = lane >> 4;
  const int wm = (wave >> 1) * 64, wn = (wave & 1) * 32;
  const int bx = blockIdx.x;
  const int sel = blockIdx.y >> 4;
  const int by = blockIdx.y & 15;
  const int K = 1024, N = 1024;

  const unsigned short* W = (sel == 0) ? Wq : (sel == 1) ? Wk : Wv;
  const float* bias = (sel == 0) ? bq : (sel == 1) ? bk : bv;

  const unsigned short* Abase = A + (size_t)bx * 128 * K;
  const unsigned short* Bbase = W + (size_t)by * 64 * K;

  GEMM_CORE_128x64(Abase, Bbase, K)

  const float qs = (sel == 0) ? 0.125f : 1.0f;  // fold attention 1/sqrt(hd) into Q
#pragma unroll
  for (int j = 0; j < 2; ++j) {
    const int cn = by * 64 + wn + j * 16 + l15;
    const float bj = bias[cn];
#pragma unroll
    for (int i = 0; i < 4; ++i) {
      const int r0 = bx * 128 + wm + i * 16 + quad * 4;
#pragma unroll
      for (int r = 0; r < 4; ++r) {
        const int row = r0 + r;
        const float v = acc[i][j][r] + bj;
        if (sel == 2) {
          Vt[((size_t)(row >> 13) * 1024 + cn) * 8192 + (row & 8191)] = f2bf_bits(v);
        } else {
          unsigned short* O = sel ? Ko : Qo;
          O[(size_t)row * N + cn] = f2bf_bits(v * qs);
        }
      }
    }
  }
}

// Output GEMM: fp32 out = A * Wo^T + bo, 128x64 tiles
__global__ __launch_bounds__(256, 5) void gemm_out(const unsigned short* __restrict__ A,
                                                   const unsigned short* __restrict__ B,
                                                   const float* __restrict__ bias,
                                                   float* __restrict__ Cf) {
  __shared__ unsigned short Al[128 * 64];
  __shared__ unsigned short Bl[64 * 64];
  const int tid = threadIdx.x;
  const int lane = tid & 63, wave = tid >> 6;
  const int l15 = lane & 15, quad = lane >> 4;
  const int wm = (wave >> 1) * 64, wn = (wave & 1) * 32;
  const int bx = blockIdx.x, by = blockIdx.y;
  const int K = 1024, N = 1024;

  const unsigned short* Abase = A + (size_t)bx * 128 * K;
  const unsigned short* Bbase = B + (size_t)by * 64 * K;

  GEMM_CORE_128x64(Abase, Bbase, K)

#pragma unroll
  for (int j = 0; j < 2; ++j) {
    const int cn = by * 64 + wn + j * 16 + l15;
    const float bj = bias[cn];
#pragma unroll
    for (int i = 0; i < 4; ++i) {
      const int r0 = bx * 128 + wm + i * 16 + quad * 4;
#pragma unroll
      for (int r = 0; r < 4; ++r) Cf[(size_t)(r0 + r) * N + cn] = acc[i][j][r] + bj;
    }
  }
}

// ---------------- attention ----------------
// Window-mask identity: dd+128 = p*32 + tt*16 + quad*4 + r - l15  (n, qt cancel).
// => interior blocks need masks only at p==0 (c>=l15) and p==8 (c<=l15).
// MM: 0 = none, 1 = low edge (p==0), 2 = high edge (p==8), 3 = full (boundary blocks).
template <int MM>
__device__ __forceinline__ void attn_step(int p, int base_row, int krel0, int qp, int quad,
                                          int l15, const unsigned short* __restrict__ Kl,
                                          const s16x8& bq0, const s16x8& bq1,
                                          unsigned short* __restrict__ strip,
                                          const unsigned short* __restrict__ Vbase,
                                          f32x4 (&o)[4], float& lsum, s16x8 (&vf)[4]) {
  // ---- S^T tiles ----
  f32x4 st[2];
#pragma unroll
  for (int tt = 0; tt < 2; ++tt) {
    const int rel = krel0 + p * 32 + tt * 16 + l15;  // always in [0,384)
    const int sw = rel & 7;
    const s16x8 ka0 = *(const s16x8*)&Kl[(rel * 8 + (quad ^ sw)) * 8];
    const s16x8 ka1 = *(const s16x8*)&Kl[(rel * 8 + ((4 + quad) ^ sw)) * 8];
    f32x4 a = (f32x4){0.f, 0.f, 0.f, 0.f};
    a = MFMA16(ka0, bq0, a);
    a = MFMA16(ka1, bq1, a);
    st[tt] = a;
  }
  // ---- prefetch next-p V frags (independent of exp chain) ----
  s16x8 vn[4];
  if (MM != 2) {
    int kc = base_row + krel0 + (p + 1) * 32 + quad * 8;
    if (MM == 3) kc = max(kc, 0);
    kc = min(kc, 8184);
#pragma unroll
    for (int dt = 0; dt < 4; ++dt)
      vn[dt] = *(const s16x8*)(Vbase + (size_t)(dt * 16 + l15) * 8192 + kc);
  }
  // ---- exp (+ mask per MM) -> bf16 strip ----
  ushort4 w0, w1;
#pragma unroll
  for (int tt = 0; tt < 2; ++tt) {
    unsigned short* wp = tt ? (unsigned short*)&w1 : (unsigned short*)&w0;
#pragma unroll
    for (int r = 0; r < 4; ++r) {
      const int c = tt * 16 + quad * 4 + r;
      float pv;
      if (MM == 0) {
        pv = __expf(st[tt][r]);
      } else if (MM == 1) {
        pv = (c >= l15) ? __expf(st[tt][r]) : 0.f;
      } else if (MM == 2) {
        pv = (c <= l15) ? __expf(st[tt][r]) : 0.f;
      } else {
        const int kp = base_row + krel0 + p * 32 + c;
        const bool ok = ((unsigned)(p * 32 + c - l15) <= 256u) && (kp >= 0) && (kp < 8192);
        pv = ok ? __expf(st[tt][r]) : 0.f;
      }
      lsum += pv;
      wp[r] = f2bf_bits(pv);
    }
  }
  *(ushort4*)&strip[l15 * 40 + quad * 4] = w0;
  *(ushort4*)&strip[l15 * 40 + 16 + quad * 4] = w1;
  const s16x8 pf = *(const s16x8*)&strip[l15 * 40 + quad * 8];
  // ---- PV with current V frags ----
#pragma unroll
  for (int dt = 0; dt < 4; ++dt) o[dt] = MFMA16(vf[dt], pf, o[dt]);
  if (MM != 2) {
#pragma unroll
    for (int dt = 0; dt < 4; ++dt) vf[dt] = vn[dt];
  }
}

template <bool EDGE>
__global__ __launch_bounds__(256, 3) void attn_kernel(const unsigned short* __restrict__ Q,
                                                      const unsigned short* __restrict__ Km,
                                                      const unsigned short* __restrict__ Vt,
                                                      unsigned short* __restrict__ O,
                                                      int n_mul, int n_off) {
  const int n = blockIdx.x * n_mul + n_off;
  const int bh = blockIdx.y;
  const int b = bh >> 4, h = bh & 15;
  const int tid = threadIdx.x, lane = tid & 63, wave = tid >> 6;
  const int l15 = lane & 15, quad = lane >> 4;

  __shared__ unsigned short Kl[384 * 64];   // 48 KB, chunk-swizzled
  __shared__ unsigned short Ps[4][16 * 40]; // per-wave P strip

  const int base_row = n * 128 - 128;

  // stage K ctx (interior: all 384 rows valid, no clamp)
  for (int i = 0; i < 12; ++i) {
    const int c = i * 256 + tid;
    const int row = c >> 3;
    const int qc = (c & 7) ^ (row & 7);
    int gr = base_row + row;
    if (EDGE) gr = min(max(gr, 0), 8191);  // invalid rows masked at use
    gl_lds16(Km + (size_t)(b * 8192 + gr) * 1024 + h * 64 + qc * 8, &Kl[c * 8]);
  }
  __syncthreads();

  const unsigned short* Vbase = Vt + (size_t)bh * 64 * 8192;
  unsigned short* strip = &Ps[wave][0];

  for (int mt = 0; mt < 2; ++mt) {
    const int qt = wave * 2 + mt;
    const int qp = n * 128 + qt * 16 + l15;
    const int krel0 = qt * 16;

    const unsigned short* qptr = Q + (size_t)(b * 8192 + qp) * 1024 + h * 64 + quad * 8;
    const s16x8 bq0 = *(const s16x8*)qptr;
    const s16x8 bq1 = *(const s16x8*)(qptr + 32);

    f32x4 o[4];
#pragma unroll
    for (int dt = 0; dt < 4; ++dt) o[dt] = (f32x4){0.f, 0.f, 0.f, 0.f};
    float lsum = 0.f;

    // preload V frags for p=0
    s16x8 vf[4];
    {
      int kc = base_row + krel0 + quad * 8;
      if (EDGE) kc = min(max(kc, 0), 8184);
#pragma unroll
      for (int dt = 0; dt < 4; ++dt)
        vf[dt] = *(const s16x8*)(Vbase + (size_t)(dt * 16 + l15) * 8192 + kc);
    }

    if (EDGE) {
#pragma unroll 1
      for (int p = 0; p < 9; ++p)
        attn_step<3>(p, base_row, krel0, qp, quad, l15, Kl, bq0, bq1, strip, Vbase, o, lsum, vf);
    } else {
      attn_step<1>(0, base_row, krel0, qp, quad, l15, Kl, bq0, bq1, strip, Vbase, o, lsum, vf);
#pragma unroll 1
      for (int p = 1; p < 8; ++p)
        attn_step<0>(p, base_row, krel0, qp, quad, l15, Kl, bq0, bq1, strip, Vbase, o, lsum, vf);
      attn_step<2>(8, base_row, krel0, qp, quad, l15, Kl, bq0, bq1, strip, Vbase, o, lsum, vf);
    }

    lsum += __shfl_xor(lsum, 16, 64);
    lsum += __shfl_xor(lsum, 32, 64);
    const float rinv = 1.f / lsum;
    unsigned short* obase = O + (size_t)(b * 8192 + qp) * 1024 + h * 64;
#pragma unroll
    for (int dt = 0; dt < 4; ++dt) {
      ushort4 w;
      unsigned short* wp = (unsigned short*)&w;
#pragma unroll
      for (int r = 0; r < 4; ++r) wp[r] = f2bf_bits(o[dt][r] * rinv);
      *(ushort4*)(obase + dt * 16 + quad * 4) = w;
    }
  }
}

extern "C" void kernel_launch(void* const* d_in, const int* in_sizes, int n_in, void* d_out,
                              int out_size, void* d_ws, size_t ws_size, hipStream_t stream) {
  const float* x = (const float*)d_in[0];
  const float* Wq = (const float*)d_in[1];
  const float* bq = (const float*)d_in[2];
  const float* Wk = (const float*)d_in[3];
  const float* bk = (const float*)d_in[4];
  const float* Wv = (const float*)d_in[5];
  const float* bv = (const float*)d_in[6];
  const float* Wo = (const float*)d_in[7];
  const float* bo = (const float*)d_in[8];
  float* out = (float*)d_out;

  const int M = 16384, D = 1024;

  unsigned short* xb = (unsigned short*)d_ws;  // [16384,1024] bf16
  unsigned short* qb = xb + (size_t)M * D;     // [16384,1024] (pre-scaled by 1/8)
  unsigned short* kb = qb + (size_t)M * D;     // [16384,1024]
  unsigned short* vt = kb + (size_t)M * D;     // [2048,8192] (V transposed)
  unsigned short* ab = vt + (size_t)M * D;     // [16384,1024] attention out
  unsigned short* wqb = ab + (size_t)M * D;    // weights bf16
  unsigned short* wkb = wqb + (size_t)D * D;
  unsigned short* wvb = wkb + (size_t)D * D;
  unsigned short* wob = wvb + (size_t)D * D;

  f2bf_kernel<<<16384, 256, 0, stream>>>(x, xb, M * D / 4);
  f2bf_w4<<<dim3(1024, 4), 256, 0, stream>>>(Wq, Wk, Wv, Wo, wqb, wkb, wvb, wob);

  gemm_qkv<<<dim3(M / 128, 48), 256, 0, stream>>>(xb, wqb, wkb, wvb, bq, bk, bv, qb, kb, vt);

  attn_kernel<false><<<dim3(62, 32), 256, 0, stream>>>(qb, kb, vt, ab, 1, 1);
  attn_kernel<true><<<dim3(2, 32), 256, 0, stream>>>(qb, kb, vt, ab, 63, 0);

  gemm_out<<<dim3(M / 128, D / 64), 256, 0, stream>>>(ab, wob, bo, out);
}